// Round 9
// baseline (224.075 us; speedup 1.0000x reference)
//
#include <hip/hip_runtime.h>
#include <stdint.h>

#define N_KERNELS 10000
#define NCHUNK 56            // >= sum_g ceil(size_g/256) worst case
#define RNG_STEPS 40         // 256 lanes * 40 next64 = 20480 u32 draws >= 20000
#define CH_ALLOC 1312        // shorts per (copy,channel); mult of 4 (8B align)
#define PP_STRIDE (3 * CH_ALLOC)
#define NPHASE 4

typedef unsigned __int128 u128;
typedef __attribute__((ext_vector_type(4)))  short short4v;
typedef __attribute__((ext_vector_type(8)))  short short8;
typedef __attribute__((ext_vector_type(16))) float floatx16;

// ---------------------------------------------------------------------------
// Setup: (1) numpy default_rng(0) -> PCG64 -> integers(0,3) x10000,
// integers(0,5) x10000 (verified R1-R8). (2) bucket by (k,d); chunk table
// sched[ci] = int4{ k, log2(d), list_start, valid } (valid==0 -> dead).
// ---------------------------------------------------------------------------
__global__ void setup_kernel(int* __restrict__ karr, int* __restrict__ darr,
                             int* __restrict__ list, int* __restrict__ sched) {
    const u128 MULT = (((u128)0x2360ED051FC65DA4ULL) << 64) | 0x4385DF649FCCF645ULL;
    const int tid = threadIdx.x;

    uint32_t hc = 0x43b0d7e5u;                    // INIT_A
    auto hashmix = [&hc](uint32_t v) -> uint32_t {
        v ^= hc; hc *= 0x931e8875u;               // MULT_A
        v *= hc; v ^= v >> 16; return v;
    };
    uint32_t pool[4];
    pool[0] = hashmix(0u);
    pool[1] = hashmix(0u);
    pool[2] = hashmix(0u);
    pool[3] = hashmix(0u);
    for (int s = 0; s < 4; s++)
        for (int dd = 0; dd < 4; dd++)
            if (s != dd) {
                uint32_t hv = hashmix(pool[s]);
                uint32_t rr = 0xca01f9ddu * pool[dd] - 0x4973f715u * hv;
                rr ^= rr >> 16;
                pool[dd] = rr;
            }
    uint32_t st[8];
    uint32_t hcb = 0x8b51f9ddu;                   // INIT_B
    for (int i = 0; i < 8; i++) {
        uint32_t dv = pool[i & 3];
        dv ^= hcb; hcb *= 0x58f38dedu;            // MULT_B
        dv *= hcb; dv ^= dv >> 16;
        st[i] = dv;
    }
    uint64_t w0 = (uint64_t)st[0] | ((uint64_t)st[1] << 32);
    uint64_t w1 = (uint64_t)st[2] | ((uint64_t)st[3] << 32);
    uint64_t w2 = (uint64_t)st[4] | ((uint64_t)st[5] << 32);
    uint64_t w3 = (uint64_t)st[6] | ((uint64_t)st[7] << 32);
    u128 initstate = (((u128)w0) << 64) | w1;
    u128 initseq   = (((u128)w2) << 64) | w3;

    u128 inc   = (initseq << 1) | 1;
    u128 state = 0;
    state = state * MULT + inc;
    state += initstate;
    state = state * MULT + inc;

    u128 Ae = 1, Ce = 0, Ab = MULT, Cb = inc;
    unsigned e = (unsigned)(tid * RNG_STEPS);
    while (e) {
        if (e & 1u) { Ae = Ab * Ae; Ce = Ab * Ce + Cb; }
        Cb = Ab * Cb + Cb;
        Ab = Ab * Ab;
        e >>= 1;
    }
    u128 s = Ae * state + Ce;

    int base = tid * (2 * RNG_STEPS);
    for (int t = 0; t < RNG_STEPS; t++) {
        s = s * MULT + inc;
        uint64_t hi = (uint64_t)(s >> 64), lo = (uint64_t)s;
        unsigned rot = (unsigned)(hi >> 58);
        uint64_t v = hi ^ lo;
        uint64_t o = (v >> rot) | (v << ((64u - rot) & 63u));
        uint32_t d0 = (uint32_t)o;
        uint32_t d1 = (uint32_t)(o >> 32);
        int i0 = base + 2 * t;
        if (i0 < 10000)       karr[i0] = (int)(((uint64_t)d0 * 3u) >> 32);
        else if (i0 < 20000)  darr[i0 - 10000] = (int)(((uint64_t)d0 * 5u) >> 32);
        int i1 = i0 + 1;
        if (i1 < 10000)       karr[i1] = (int)(((uint64_t)d1 * 3u) >> 32);
        else if (i1 < 20000)  darr[i1 - 10000] = (int)(((uint64_t)d1 * 5u) >> 32);
    }

    __syncthreads();   // karr/darr visible to the whole (single) block

    __shared__ int cnt[16], off[16], cur[16];
    if (tid < 16) cnt[tid] = 0;
    __syncthreads();
    for (int i = tid; i < N_KERNELS; i += 256)
        atomicAdd(&cnt[karr[i] * 5 + darr[i]], 1);
    __syncthreads();
    if (tid == 0) { int o = 0; for (int g = 0; g < 15; g++) { off[g] = o; o += cnt[g]; } }
    __syncthreads();
    if (tid < 16) cur[tid] = 0;
    __syncthreads();
    for (int i = tid; i < N_KERNELS; i += 256) {
        int g = karr[i] * 5 + darr[i];
        list[off[g] + atomicAdd(&cur[g], 1)] = i;
    }
    __syncthreads();
    if (tid == 0) {
        const int kv[3] = {7, 9, 11};
        int ci = 0;
        for (int g = 0; g < 15; g++) {
            int sz = cnt[g];
            for (int s2 = 0; s2 < sz; s2 += 256) {
                int4 e2;
                e2.x = kv[g / 5];
                e2.y = g % 5;
                e2.z = off[g] + s2;
                e2.w = (sz - s2 < 256) ? (sz - s2) : 256;
                reinterpret_cast<int4*>(sched)[ci++] = e2;
            }
        }
        for (; ci < NCHUNK; ci++) {
            int4 e2; e2.x = 0; e2.y = 0; e2.z = 0; e2.w = 0;
            reinterpret_cast<int4*>(sched)[ci] = e2;
        }
    }
}

// ---------------------------------------------------------------------------
// Main: bf16 MFMA Toeplitz GEMM (R6 coverage structure, verified correct).
// R9 perf changes: (a) persistent bias tiles BT0/BT1 as the C operand of the
// first MFMA of each chain -> zero per-iter accumulator init movs;
// (b) sign-count via funnel-shift mask (v_alignbit) + popcount;
// (c) C0 chain completes before C1 chain so stats(C0) on the VALU pipe
// overlaps C1's MFMAs on the matrix pipe.
// ---------------------------------------------------------------------------
__device__ __forceinline__ uint16_t f32_to_bf16(float v) {
    uint32_t u = __builtin_bit_cast(uint32_t, v);
    return (uint16_t)((u + 0x7FFFu + ((u >> 16) & 1u)) >> 16);
}

__device__ __forceinline__ void stat16(const floatx16& C, float& mx, int& cnt) {
    // max: v_max3-fusable triple tree (8 ops)
    float g0 = fmaxf(fmaxf(C[0],  C[1]),  C[2]);
    float g1 = fmaxf(fmaxf(C[3],  C[4]),  C[5]);
    float g2 = fmaxf(fmaxf(C[6],  C[7]),  C[8]);
    float g3 = fmaxf(fmaxf(C[9],  C[10]), C[11]);
    float g4 = fmaxf(fmaxf(C[12], C[13]), C[14]);
    float h0 = fmaxf(fmaxf(g0, g1), g2);
    float h1 = fmaxf(fmaxf(g3, g4), C[15]);
    mx = fmaxf(mx, fmaxf(h0, h1));
    // negative-count: shift sign bits into 2 masks ((m<<1)|(u>>31) ->
    // v_alignbit_b32, 1 op/elem, two independent 8-deep chains), then popcount
    uint32_t mA = 0, mB = 0;
    #pragma unroll
    for (int i = 0; i < 16; i += 2) {
        mA = (mA << 1) | (__builtin_bit_cast(uint32_t, C[i])     >> 31);
        mB = (mB << 1) | (__builtin_bit_cast(uint32_t, C[i + 1]) >> 31);
    }
    cnt += __popc(mA) + __popc(mB);
}

template <int K, int D>
__device__ __forceinline__ void body(const float* __restrict__ x,
                                     const float* __restrict__ wgt,
                                     const float* __restrict__ bias,
                                     const int* __restrict__ list,
                                     int lstart, int valid,
                                     float* __restrict__ out,
                                     short* __restrict__ xs,   // [4][3][CH_ALLOC]
                                     int b) {
    constexpr int H   = (K - 1) / 2;
    constexpr int Q   = 1024 / D;
    constexpr int S   = Q + 16;                    // residue slot stride (gap 16)
    constexpr int RS  = (D <= 4) ? 8 : (D == 8 ? 4 : 2);   // row stride (positions)
    constexpr int PH  = RS;                        // sub-phases per range
    constexpr int NRG = (D <= 4) ? 4 : D;          // ranges
    constexpr int RPERRES = (D <= 4) ? (4 / D) : 1;

    const int tid   = threadIdx.x;
    const int lane  = tid & 63;
    const int wave  = tid >> 6;
    const int jbase = (lane >> 5) * 8;             // k-half offset (0 or 8; ==0 mod 4)

    // ---- stage: write the 4 phase-copies of the padded bf16 signal --------
    for (int idx = tid; idx < 3 * (CH_ALLOC + NPHASE); idx += 256) {
        int c = idx / (CH_ALLOC + NPHASE);
        int P = idx - c * (CH_ALLOC + NPHASE);
        float v = 0.f;
        int y = P - 8;
        if (y >= 0) {
            int r = y / S;
            int q = y - r * S;
            if (r < D && q < Q) v = x[((size_t)b * 3 + c) * 1024 + r + D * q];
        }
        short hv = (short)f32_to_bf16(v);
        #pragma unroll
        for (int pp = 0; pp < NPHASE; ++pp) {
            int e = P - pp;
            if (e >= 0 && e < CH_ALLOC)
                xs[pp * PP_STRIDE + c * CH_ALLOC + e] = hv;
        }
    }

    // ---- per-lane B fragments (weights, hi/lo split), overlap staging -----
    int i0 = wave * 64 + (lane & 31);
    int i1 = i0 + 32;
    int n0 = list[lstart + (i0 < valid ? i0 : valid - 1)];
    int n1 = list[lstart + (i1 < valid ? i1 : valid - 1)];
    short8 whi[2][3], wlo[2][3];
    #pragma unroll
    for (int t2 = 0; t2 < 2; ++t2) {
        int n = t2 ? n1 : n0;
        #pragma unroll
        for (int c = 0; c < 3; ++c) {
            #pragma unroll
            for (int u = 0; u < 8; ++u) {
                int j = jbase + u;
                float wv = (j < 11) ? wgt[n * 33 + c * 11 + j] : 0.f;
                uint16_t h = f32_to_bf16(wv);
                float hf = __builtin_bit_cast(float, (uint32_t)h << 16);
                uint16_t l = f32_to_bf16(wv - hf);
                whi[t2][c][u] = (short)h;
                wlo[t2][c][u] = (short)l;
            }
        }
    }
    float bv0 = bias[n0], bv1 = bias[n1];

    // persistent bias tiles: C operand of each chain's FIRST MFMA (no per-iter
    // accumulator init; MFMA dest != C operand is legal)
    floatx16 BT0, BT1;
    #pragma unroll
    for (int i = 0; i < 16; ++i) { BT0[i] = bv0; BT1[i] = bv1; }

    __syncthreads();

    // ---- main loop: NRG ranges x PH sub-phases, no further barriers -------
    float mx0 = -3.402823466e38f, mx1 = -3.402823466e38f;
    int cnt0 = 0, cnt1 = 0;                        // negative counts
    const int m31 = lane & 31;                     // A row / C-D column index

    #pragma unroll 1
    for (int ri = 0; ri < NRG; ++ri) {
        const int q0 = (D <= 4) ? (8 + (ri / RPERRES) * S + (ri % RPERRES) * 256)
                                : (8 + ri * S);
        #pragma unroll 1
        for (int p = 0; p < PH; ++p) {
            // row m covers position q0-8 + p + RS*m (all valid by construction)
            const int F  = q0 + p - H + RS * m31;  // window start (array index)
            const int pp = F & (NPHASE - 1);       // per-lane phase copy
            const int e  = (F & ~(NPHASE - 1)) + jbase;  // 8B-aligned elem offset
            const short* src = xs + pp * PP_STRIDE + e;
            short4v l0 = *reinterpret_cast<const short4v*>(src);
            short4v h0 = *reinterpret_cast<const short4v*>(src + 4);
            short4v l1 = *reinterpret_cast<const short4v*>(src + CH_ALLOC);
            short4v h1 = *reinterpret_cast<const short4v*>(src + CH_ALLOC + 4);
            short4v l2 = *reinterpret_cast<const short4v*>(src + 2 * CH_ALLOC);
            short4v h2 = *reinterpret_cast<const short4v*>(src + 2 * CH_ALLOC + 4);
            short8 a0 = __builtin_shufflevector(l0, h0, 0, 1, 2, 3, 4, 5, 6, 7);
            short8 a1 = __builtin_shufflevector(l1, h1, 0, 1, 2, 3, 4, 5, 6, 7);
            short8 a2 = __builtin_shufflevector(l2, h2, 0, 1, 2, 3, 4, 5, 6, 7);

            // C0 chain first (seeded by BT0)...
            floatx16 C0, C1;
            C0 = __builtin_amdgcn_mfma_f32_32x32x16_bf16(a0, whi[0][0], BT0, 0, 0, 0);
            C0 = __builtin_amdgcn_mfma_f32_32x32x16_bf16(a0, wlo[0][0], C0, 0, 0, 0);
            C0 = __builtin_amdgcn_mfma_f32_32x32x16_bf16(a1, whi[0][1], C0, 0, 0, 0);
            C0 = __builtin_amdgcn_mfma_f32_32x32x16_bf16(a1, wlo[0][1], C0, 0, 0, 0);
            C0 = __builtin_amdgcn_mfma_f32_32x32x16_bf16(a2, whi[0][2], C0, 0, 0, 0);
            C0 = __builtin_amdgcn_mfma_f32_32x32x16_bf16(a2, wlo[0][2], C0, 0, 0, 0);
            // ...then C1 chain (stats of C0 overlap these on the VALU pipe)
            C1 = __builtin_amdgcn_mfma_f32_32x32x16_bf16(a0, whi[1][0], BT1, 0, 0, 0);
            C1 = __builtin_amdgcn_mfma_f32_32x32x16_bf16(a0, wlo[1][0], C1, 0, 0, 0);
            C1 = __builtin_amdgcn_mfma_f32_32x32x16_bf16(a1, whi[1][1], C1, 0, 0, 0);
            C1 = __builtin_amdgcn_mfma_f32_32x32x16_bf16(a1, wlo[1][1], C1, 0, 0, 0);
            C1 = __builtin_amdgcn_mfma_f32_32x32x16_bf16(a2, whi[1][2], C1, 0, 0, 0);
            C1 = __builtin_amdgcn_mfma_f32_32x32x16_bf16(a2, wlo[1][2], C1, 0, 0, 0);

            stat16(C0, mx0, cnt0);
            stat16(C1, mx1, cnt1);
        }
    }

    // ---- merge complementary row halves across the (L, L^32) lane pair ----
    mx0  = fmaxf(mx0, __shfl_xor(mx0, 32));
    mx1  = fmaxf(mx1, __shfl_xor(mx1, 32));
    cnt0 += __shfl_xor(cnt0, 32);
    cnt1 += __shfl_xor(cnt1, 32);

    if (lane < 32) {
        float2* ob = reinterpret_cast<float2*>(out + (size_t)b * (2 * N_KERNELS));
        ob[n0] = make_float2(mx0, (float)(1024 - cnt0) * (1.0f / 1024.0f));
        ob[n1] = make_float2(mx1, (float)(1024 - cnt1) * (1.0f / 1024.0f));
    }
}

__global__ __launch_bounds__(256, 4)
void rocket_main(const float* __restrict__ x, const float* __restrict__ wgt,
                 const float* __restrict__ bias, const int* __restrict__ list,
                 const int* __restrict__ sched, float* __restrict__ out) {
    __shared__ __align__(16) short xs[NPHASE * PP_STRIDE];   // 31.5 KB
    int4 e = reinterpret_cast<const int4*>(sched)[blockIdx.x];
    if (e.w == 0) return;                                // dead chunk — uniform exit
    int b = blockIdx.y;
    int kc = e.x, ld2 = e.y, lstart = e.z, valid = e.w;
    switch (kc * 8 + ld2) {
        case 7*8+0:  body<7, 1 >(x, wgt, bias, list, lstart, valid, out, xs, b); break;
        case 7*8+1:  body<7, 2 >(x, wgt, bias, list, lstart, valid, out, xs, b); break;
        case 7*8+2:  body<7, 4 >(x, wgt, bias, list, lstart, valid, out, xs, b); break;
        case 7*8+3:  body<7, 8 >(x, wgt, bias, list, lstart, valid, out, xs, b); break;
        case 7*8+4:  body<7, 16>(x, wgt, bias, list, lstart, valid, out, xs, b); break;
        case 9*8+0:  body<9, 1 >(x, wgt, bias, list, lstart, valid, out, xs, b); break;
        case 9*8+1:  body<9, 2 >(x, wgt, bias, list, lstart, valid, out, xs, b); break;
        case 9*8+2:  body<9, 4 >(x, wgt, bias, list, lstart, valid, out, xs, b); break;
        case 9*8+3:  body<9, 8 >(x, wgt, bias, list, lstart, valid, out, xs, b); break;
        case 9*8+4:  body<9, 16>(x, wgt, bias, list, lstart, valid, out, xs, b); break;
        case 11*8+0: body<11,1 >(x, wgt, bias, list, lstart, valid, out, xs, b); break;
        case 11*8+1: body<11,2 >(x, wgt, bias, list, lstart, valid, out, xs, b); break;
        case 11*8+2: body<11,4 >(x, wgt, bias, list, lstart, valid, out, xs, b); break;
        case 11*8+3: body<11,8 >(x, wgt, bias, list, lstart, valid, out, xs, b); break;
        default:     body<11,16>(x, wgt, bias, list, lstart, valid, out, xs, b); break;
    }
}

extern "C" void kernel_launch(void* const* d_in, const int* in_sizes, int n_in,
                              void* d_out, int out_size, void* d_ws, size_t ws_size,
                              hipStream_t stream) {
    const float* x   = (const float*)d_in[0];
    const float* w   = (const float*)d_in[1];
    const float* b   = (const float*)d_in[2];
    float* out = (float*)d_out;

    int* wsi  = (int*)d_ws;
    int* karr = wsi;            // 10000
    int* darr = wsi + 10000;    // 10000
    int* list = wsi + 20000;    // 10000
    int* schd = wsi + 30000;    // NCHUNK*4 ints (16B aligned)

    hipLaunchKernelGGL(setup_kernel, dim3(1), dim3(256), 0, stream,
                       karr, darr, list, schd);
    hipLaunchKernelGGL(rocket_main,  dim3(NCHUNK, 64), dim3(256), 0, stream,
                       x, w, b, list, schd, out);
}

// Round 10
// 188.761 us; speedup vs baseline: 1.1871x; 1.1871x over previous
//
#include <hip/hip_runtime.h>
#include <stdint.h>

#define N_KERNELS 10000
#define NCHUNK 56            // >= sum_g ceil(size_g/256) worst case
#define RNG_STEPS 40         // 256 lanes * 40 next64 = 20480 u32 draws >= 20000
#define CH_ALLOC 1312        // shorts per (copy,channel); mult of 4 (8B granules)
#define PP_STRIDE (3 * CH_ALLOC)
#define NPHASE 4

typedef unsigned __int128 u128;
typedef __attribute__((ext_vector_type(4)))  short short4v;
typedef __attribute__((ext_vector_type(8)))  short short8;
typedef __attribute__((ext_vector_type(16))) float floatx16;

// ---------------------------------------------------------------------------
// Setup: (1) numpy default_rng(0) -> PCG64 -> integers(0,3) x10000,
// integers(0,5) x10000 (verified R1-R9). (2) bucket by (k,d); chunk table
// sched[ci] = int4{ k, log2(d), list_start, valid } (valid==0 -> dead).
// ---------------------------------------------------------------------------
__global__ void setup_kernel(int* __restrict__ karr, int* __restrict__ darr,
                             int* __restrict__ list, int* __restrict__ sched) {
    const u128 MULT = (((u128)0x2360ED051FC65DA4ULL) << 64) | 0x4385DF649FCCF645ULL;
    const int tid = threadIdx.x;

    uint32_t hc = 0x43b0d7e5u;                    // INIT_A
    auto hashmix = [&hc](uint32_t v) -> uint32_t {
        v ^= hc; hc *= 0x931e8875u;               // MULT_A
        v *= hc; v ^= v >> 16; return v;
    };
    uint32_t pool[4];
    pool[0] = hashmix(0u);
    pool[1] = hashmix(0u);
    pool[2] = hashmix(0u);
    pool[3] = hashmix(0u);
    for (int s = 0; s < 4; s++)
        for (int dd = 0; dd < 4; dd++)
            if (s != dd) {
                uint32_t hv = hashmix(pool[s]);
                uint32_t rr = 0xca01f9ddu * pool[dd] - 0x4973f715u * hv;
                rr ^= rr >> 16;
                pool[dd] = rr;
            }
    uint32_t st[8];
    uint32_t hcb = 0x8b51f9ddu;                   // INIT_B
    for (int i = 0; i < 8; i++) {
        uint32_t dv = pool[i & 3];
        dv ^= hcb; hcb *= 0x58f38dedu;            // MULT_B
        dv *= hcb; dv ^= dv >> 16;
        st[i] = dv;
    }
    uint64_t w0 = (uint64_t)st[0] | ((uint64_t)st[1] << 32);
    uint64_t w1 = (uint64_t)st[2] | ((uint64_t)st[3] << 32);
    uint64_t w2 = (uint64_t)st[4] | ((uint64_t)st[5] << 32);
    uint64_t w3 = (uint64_t)st[6] | ((uint64_t)st[7] << 32);
    u128 initstate = (((u128)w0) << 64) | w1;
    u128 initseq   = (((u128)w2) << 64) | w3;

    u128 inc   = (initseq << 1) | 1;
    u128 state = 0;
    state = state * MULT + inc;
    state += initstate;
    state = state * MULT + inc;

    u128 Ae = 1, Ce = 0, Ab = MULT, Cb = inc;
    unsigned e = (unsigned)(tid * RNG_STEPS);
    while (e) {
        if (e & 1u) { Ae = Ab * Ae; Ce = Ab * Ce + Cb; }
        Cb = Ab * Cb + Cb;
        Ab = Ab * Ab;
        e >>= 1;
    }
    u128 s = Ae * state + Ce;

    int base = tid * (2 * RNG_STEPS);
    for (int t = 0; t < RNG_STEPS; t++) {
        s = s * MULT + inc;
        uint64_t hi = (uint64_t)(s >> 64), lo = (uint64_t)s;
        unsigned rot = (unsigned)(hi >> 58);
        uint64_t v = hi ^ lo;
        uint64_t o = (v >> rot) | (v << ((64u - rot) & 63u));
        uint32_t d0 = (uint32_t)o;
        uint32_t d1 = (uint32_t)(o >> 32);
        int i0 = base + 2 * t;
        if (i0 < 10000)       karr[i0] = (int)(((uint64_t)d0 * 3u) >> 32);
        else if (i0 < 20000)  darr[i0 - 10000] = (int)(((uint64_t)d0 * 5u) >> 32);
        int i1 = i0 + 1;
        if (i1 < 10000)       karr[i1] = (int)(((uint64_t)d1 * 3u) >> 32);
        else if (i1 < 20000)  darr[i1 - 10000] = (int)(((uint64_t)d1 * 5u) >> 32);
    }

    __syncthreads();   // karr/darr visible to the whole (single) block

    __shared__ int cnt[16], off[16], cur[16];
    if (tid < 16) cnt[tid] = 0;
    __syncthreads();
    for (int i = tid; i < N_KERNELS; i += 256)
        atomicAdd(&cnt[karr[i] * 5 + darr[i]], 1);
    __syncthreads();
    if (tid == 0) { int o = 0; for (int g = 0; g < 15; g++) { off[g] = o; o += cnt[g]; } }
    __syncthreads();
    if (tid < 16) cur[tid] = 0;
    __syncthreads();
    for (int i = tid; i < N_KERNELS; i += 256) {
        int g = karr[i] * 5 + darr[i];
        list[off[g] + atomicAdd(&cur[g], 1)] = i;
    }
    __syncthreads();
    if (tid == 0) {
        const int kv[3] = {7, 9, 11};
        int ci = 0;
        for (int g = 0; g < 15; g++) {
            int sz = cnt[g];
            for (int s2 = 0; s2 < sz; s2 += 256) {
                int4 e2;
                e2.x = kv[g / 5];
                e2.y = g % 5;
                e2.z = off[g] + s2;
                e2.w = (sz - s2 < 256) ? (sz - s2) : 256;
                reinterpret_cast<int4*>(sched)[ci++] = e2;
            }
        }
        for (; ci < NCHUNK; ci++) {
            int4 e2; e2.x = 0; e2.y = 0; e2.z = 0; e2.w = 0;
            reinterpret_cast<int4*>(sched)[ci] = e2;
        }
    }
}

// ---------------------------------------------------------------------------
// Main: bf16 MFMA Toeplitz GEMM (R6 coverage structure, verified correct).
// R10: (a) single-bf16 weights (wlo dropped: 6 MFMA/iter, 3-deep chains);
// (b) XOR bank swizzle on 8B granules (g ^= (g>>4)&3) in staging writes AND
// frag reads -> D<=4's 8-way conflicts become uniform ~2/bank (b64 floor);
// (c) software-pipelined frag loads: flattened 32-iter loop, ping-pong regs,
// next iter's 6 ds_read_b64 issued between the C0 and C1 MFMA chains.
// ---------------------------------------------------------------------------
__device__ __forceinline__ uint16_t f32_to_bf16(float v) {
    uint32_t u = __builtin_bit_cast(uint32_t, v);
    return (uint16_t)((u + 0x7FFFu + ((u >> 16) & 1u)) >> 16);
}

__device__ __forceinline__ void stat16(const floatx16& C, float& mx, int& cnt) {
    float g0 = fmaxf(fmaxf(C[0],  C[1]),  C[2]);
    float g1 = fmaxf(fmaxf(C[3],  C[4]),  C[5]);
    float g2 = fmaxf(fmaxf(C[6],  C[7]),  C[8]);
    float g3 = fmaxf(fmaxf(C[9],  C[10]), C[11]);
    float g4 = fmaxf(fmaxf(C[12], C[13]), C[14]);
    float h0 = fmaxf(fmaxf(g0, g1), g2);
    float h1 = fmaxf(fmaxf(g3, g4), C[15]);
    mx = fmaxf(mx, fmaxf(h0, h1));
    uint32_t mA = 0, mB = 0;
    #pragma unroll
    for (int i = 0; i < 16; i += 2) {
        mA = (mA << 1) | (__builtin_bit_cast(uint32_t, C[i])     >> 31);
        mB = (mB << 1) | (__builtin_bit_cast(uint32_t, C[i + 1]) >> 31);
    }
    cnt += __popc(mA) + __popc(mB);
}

__device__ __forceinline__ int swz_g(int g) { return g ^ ((g >> 4) & 3); }

template <int K, int D>
__device__ __forceinline__ void body(const float* __restrict__ x,
                                     const float* __restrict__ wgt,
                                     const float* __restrict__ bias,
                                     const int* __restrict__ list,
                                     int lstart, int valid,
                                     float* __restrict__ out,
                                     short* __restrict__ xs,   // [4][3][CH_ALLOC]
                                     int b) {
    constexpr int H   = (K - 1) / 2;
    constexpr int Q   = 1024 / D;
    constexpr int S   = Q + 16;                    // residue slot stride (gap 16)
    constexpr int RS  = (D <= 4) ? 8 : (D == 8 ? 4 : 2);   // row stride (positions)
    constexpr int NIT = 32;                        // total iterations (all D)

    const int tid   = threadIdx.x;
    const int lane  = tid & 63;
    const int wave  = tid >> 6;
    const int jbase = (lane >> 5) * 8;             // k-half offset (0 or 8 shorts)
    const int m31   = lane & 31;                   // A row / C-D column index

    // ---- stage: 4 phase-copies, bank-swizzled at 8B-granule level ---------
    // logical short ee of copy pp holds sig[ee+pp]; phys = swz(ee>>2)*4+(ee&3)
    for (int idx = tid; idx < 3 * (CH_ALLOC + NPHASE); idx += 256) {
        int c = idx / (CH_ALLOC + NPHASE);
        int P = idx - c * (CH_ALLOC + NPHASE);
        float v = 0.f;
        int y = P - 8;
        if (y >= 0) {
            int r = y / S;
            int q = y - r * S;
            if (r < D && q < Q) v = x[((size_t)b * 3 + c) * 1024 + r + D * q];
        }
        short hv = (short)f32_to_bf16(v);
        #pragma unroll
        for (int pp = 0; pp < NPHASE; ++pp) {
            int ee = P - pp;
            if (ee >= 0 && ee < CH_ALLOC) {
                int phys = (swz_g(ee >> 2) << 2) | (ee & 3);
                xs[pp * PP_STRIDE + c * CH_ALLOC + phys] = hv;
            }
        }
    }

    // ---- per-lane B fragments (single bf16 weights), overlap staging ------
    int i0 = wave * 64 + m31;
    int i1 = i0 + 32;
    int n0 = list[lstart + (i0 < valid ? i0 : valid - 1)];
    int n1 = list[lstart + (i1 < valid ? i1 : valid - 1)];
    short8 whi[2][3];
    #pragma unroll
    for (int t2 = 0; t2 < 2; ++t2) {
        int n = t2 ? n1 : n0;
        #pragma unroll
        for (int c = 0; c < 3; ++c) {
            #pragma unroll
            for (int u = 0; u < 8; ++u) {
                int j = jbase + u;
                float wv = (j < 11) ? wgt[n * 33 + c * 11 + j] : 0.f;
                whi[t2][c][u] = (short)f32_to_bf16(wv);
            }
        }
    }
    float bv0 = bias[n0], bv1 = bias[n1];

    floatx16 BT0, BT1;                             // persistent bias seed tiles
    #pragma unroll
    for (int i = 0; i < 16; ++i) { BT0[i] = bv0; BT1[i] = bv1; }

    __syncthreads();

    // ---- window-start index for flattened iteration it --------------------
    auto calcF = [&](int it) -> int {
        int ri, p;
        if (D <= 4)      { ri = it >> 3; p = it & 7; }
        else if (D == 8) { ri = it >> 2; p = it & 3; }
        else             { ri = it >> 1; p = it & 1; }
        int q0;
        if (D == 1)      q0 = 8 + ri * 256;
        else if (D == 2) q0 = 8 + (ri >> 1) * S + (ri & 1) * 256;
        else             q0 = 8 + ri * S;
        return q0 + p - H + RS * m31;
    };
    // swizzled 2x b64 frag load (frag = logical shorts [(F&~3)+jbase, +8))
    auto loadfrag = [&](int F, short8& A0, short8& A1, short8& A2) {
        int g0 = (F >> 2) + (jbase >> 2);
        int s0 = swz_g(g0) << 2;
        int s1 = swz_g(g0 + 1) << 2;
        const short* bp = xs + (F & 3) * PP_STRIDE;
        short4v l0 = *reinterpret_cast<const short4v*>(bp + s0);
        short4v h0 = *reinterpret_cast<const short4v*>(bp + s1);
        short4v l1 = *reinterpret_cast<const short4v*>(bp + CH_ALLOC + s0);
        short4v h1 = *reinterpret_cast<const short4v*>(bp + CH_ALLOC + s1);
        short4v l2 = *reinterpret_cast<const short4v*>(bp + 2 * CH_ALLOC + s0);
        short4v h2 = *reinterpret_cast<const short4v*>(bp + 2 * CH_ALLOC + s1);
        A0 = __builtin_shufflevector(l0, h0, 0, 1, 2, 3, 4, 5, 6, 7);
        A1 = __builtin_shufflevector(l1, h1, 0, 1, 2, 3, 4, 5, 6, 7);
        A2 = __builtin_shufflevector(l2, h2, 0, 1, 2, 3, 4, 5, 6, 7);
    };

    // ---- main loop: software-pipelined, ping-pong frag registers ----------
    float mx0 = -3.402823466e38f, mx1 = -3.402823466e38f;
    int cnt0 = 0, cnt1 = 0;                        // negative counts

    short8 a0, a1, a2, b0, b1, b2;
    loadfrag(calcF(0), a0, a1, a2);

    #pragma unroll 1
    for (int it = 0; it < NIT; ++it) {
        int itn = (it + 1 < NIT) ? it + 1 : it;    // last iter: redundant reload
        floatx16 C0, C1;
        C0 = __builtin_amdgcn_mfma_f32_32x32x16_bf16(a0, whi[0][0], BT0, 0, 0, 0);
        C0 = __builtin_amdgcn_mfma_f32_32x32x16_bf16(a1, whi[0][1], C0, 0, 0, 0);
        C0 = __builtin_amdgcn_mfma_f32_32x32x16_bf16(a2, whi[0][2], C0, 0, 0, 0);
        loadfrag(calcF(itn), b0, b1, b2);          // next iter's frags in flight
        C1 = __builtin_amdgcn_mfma_f32_32x32x16_bf16(a0, whi[1][0], BT1, 0, 0, 0);
        C1 = __builtin_amdgcn_mfma_f32_32x32x16_bf16(a1, whi[1][1], C1, 0, 0, 0);
        C1 = __builtin_amdgcn_mfma_f32_32x32x16_bf16(a2, whi[1][2], C1, 0, 0, 0);
        stat16(C0, mx0, cnt0);
        stat16(C1, mx1, cnt1);
        a0 = b0; a1 = b1; a2 = b2;
    }

    // ---- merge complementary row halves across the (L, L^32) lane pair ----
    mx0  = fmaxf(mx0, __shfl_xor(mx0, 32));
    mx1  = fmaxf(mx1, __shfl_xor(mx1, 32));
    cnt0 += __shfl_xor(cnt0, 32);
    cnt1 += __shfl_xor(cnt1, 32);

    if (lane < 32) {
        float2* ob = reinterpret_cast<float2*>(out + (size_t)b * (2 * N_KERNELS));
        ob[n0] = make_float2(mx0, (float)(1024 - cnt0) * (1.0f / 1024.0f));
        ob[n1] = make_float2(mx1, (float)(1024 - cnt1) * (1.0f / 1024.0f));
    }
}

__global__ __launch_bounds__(256, 4)
void rocket_main(const float* __restrict__ x, const float* __restrict__ wgt,
                 const float* __restrict__ bias, const int* __restrict__ list,
                 const int* __restrict__ sched, float* __restrict__ out) {
    __shared__ __align__(16) short xs[NPHASE * PP_STRIDE];   // 31.5 KB
    int4 e = reinterpret_cast<const int4*>(sched)[blockIdx.x];
    if (e.w == 0) return;                                // dead chunk — uniform exit
    int b = blockIdx.y;
    int kc = e.x, ld2 = e.y, lstart = e.z, valid = e.w;
    switch (kc * 8 + ld2) {
        case 7*8+0:  body<7, 1 >(x, wgt, bias, list, lstart, valid, out, xs, b); break;
        case 7*8+1:  body<7, 2 >(x, wgt, bias, list, lstart, valid, out, xs, b); break;
        case 7*8+2:  body<7, 4 >(x, wgt, bias, list, lstart, valid, out, xs, b); break;
        case 7*8+3:  body<7, 8 >(x, wgt, bias, list, lstart, valid, out, xs, b); break;
        case 7*8+4:  body<7, 16>(x, wgt, bias, list, lstart, valid, out, xs, b); break;
        case 9*8+0:  body<9, 1 >(x, wgt, bias, list, lstart, valid, out, xs, b); break;
        case 9*8+1:  body<9, 2 >(x, wgt, bias, list, lstart, valid, out, xs, b); break;
        case 9*8+2:  body<9, 4 >(x, wgt, bias, list, lstart, valid, out, xs, b); break;
        case 9*8+3:  body<9, 8 >(x, wgt, bias, list, lstart, valid, out, xs, b); break;
        case 9*8+4:  body<9, 16>(x, wgt, bias, list, lstart, valid, out, xs, b); break;
        case 11*8+0: body<11,1 >(x, wgt, bias, list, lstart, valid, out, xs, b); break;
        case 11*8+1: body<11,2 >(x, wgt, bias, list, lstart, valid, out, xs, b); break;
        case 11*8+2: body<11,4 >(x, wgt, bias, list, lstart, valid, out, xs, b); break;
        case 11*8+3: body<11,8 >(x, wgt, bias, list, lstart, valid, out, xs, b); break;
        default:     body<11,16>(x, wgt, bias, list, lstart, valid, out, xs, b); break;
    }
}

extern "C" void kernel_launch(void* const* d_in, const int* in_sizes, int n_in,
                              void* d_out, int out_size, void* d_ws, size_t ws_size,
                              hipStream_t stream) {
    const float* x   = (const float*)d_in[0];
    const float* w   = (const float*)d_in[1];
    const float* b   = (const float*)d_in[2];
    float* out = (float*)d_out;

    int* wsi  = (int*)d_ws;
    int* karr = wsi;            // 10000
    int* darr = wsi + 10000;    // 10000
    int* list = wsi + 20000;    // 10000
    int* schd = wsi + 30000;    // NCHUNK*4 ints (16B aligned)

    hipLaunchKernelGGL(setup_kernel, dim3(1), dim3(256), 0, stream,
                       karr, darr, list, schd);
    hipLaunchKernelGGL(rocket_main,  dim3(NCHUNK, 64), dim3(256), 0, stream,
                       x, w, b, list, schd, out);
}

// Round 11
// 188.577 us; speedup vs baseline: 1.1882x; 1.0010x over previous
//
#include <hip/hip_runtime.h>
#include <stdint.h>

#define N_KERNELS 10000
#define NCHUNK 56            // >= sum_g ceil(size_g/256) worst case
#define RNG_STEPS 40         // 256 lanes * 40 next64 = 20480 u32 draws >= 20000
#define CH_ALLOC 1312        // shorts per (copy,channel); mult of 4 (8B granules)
#define PP_STRIDE (3 * CH_ALLOC)
#define NPHASE 4

typedef unsigned __int128 u128;
typedef __attribute__((ext_vector_type(4)))  short short4v;
typedef __attribute__((ext_vector_type(8)))  short short8;
typedef __attribute__((ext_vector_type(16))) float floatx16;

// ---------------------------------------------------------------------------
// Setup: (1) numpy default_rng(0) -> PCG64 -> integers(0,3) x10000,
// integers(0,5) x10000 (verified R1-R10). (2) bucket by (k,d); chunk table
// sched[ci] = int4{ k, log2(d), list_start, valid } (valid==0 -> dead).
// ---------------------------------------------------------------------------
__global__ void setup_kernel(int* __restrict__ karr, int* __restrict__ darr,
                             int* __restrict__ list, int* __restrict__ sched) {
    const u128 MULT = (((u128)0x2360ED051FC65DA4ULL) << 64) | 0x4385DF649FCCF645ULL;
    const int tid = threadIdx.x;

    uint32_t hc = 0x43b0d7e5u;                    // INIT_A
    auto hashmix = [&hc](uint32_t v) -> uint32_t {
        v ^= hc; hc *= 0x931e8875u;               // MULT_A
        v *= hc; v ^= v >> 16; return v;
    };
    uint32_t pool[4];
    pool[0] = hashmix(0u);
    pool[1] = hashmix(0u);
    pool[2] = hashmix(0u);
    pool[3] = hashmix(0u);
    for (int s = 0; s < 4; s++)
        for (int dd = 0; dd < 4; dd++)
            if (s != dd) {
                uint32_t hv = hashmix(pool[s]);
                uint32_t rr = 0xca01f9ddu * pool[dd] - 0x4973f715u * hv;
                rr ^= rr >> 16;
                pool[dd] = rr;
            }
    uint32_t st[8];
    uint32_t hcb = 0x8b51f9ddu;                   // INIT_B
    for (int i = 0; i < 8; i++) {
        uint32_t dv = pool[i & 3];
        dv ^= hcb; hcb *= 0x58f38dedu;            // MULT_B
        dv *= hcb; dv ^= dv >> 16;
        st[i] = dv;
    }
    uint64_t w0 = (uint64_t)st[0] | ((uint64_t)st[1] << 32);
    uint64_t w1 = (uint64_t)st[2] | ((uint64_t)st[3] << 32);
    uint64_t w2 = (uint64_t)st[4] | ((uint64_t)st[5] << 32);
    uint64_t w3 = (uint64_t)st[6] | ((uint64_t)st[7] << 32);
    u128 initstate = (((u128)w0) << 64) | w1;
    u128 initseq   = (((u128)w2) << 64) | w3;

    u128 inc   = (initseq << 1) | 1;
    u128 state = 0;
    state = state * MULT + inc;
    state += initstate;
    state = state * MULT + inc;

    u128 Ae = 1, Ce = 0, Ab = MULT, Cb = inc;
    unsigned e = (unsigned)(tid * RNG_STEPS);
    while (e) {
        if (e & 1u) { Ae = Ab * Ae; Ce = Ab * Ce + Cb; }
        Cb = Ab * Cb + Cb;
        Ab = Ab * Ab;
        e >>= 1;
    }
    u128 s = Ae * state + Ce;

    int base = tid * (2 * RNG_STEPS);
    for (int t = 0; t < RNG_STEPS; t++) {
        s = s * MULT + inc;
        uint64_t hi = (uint64_t)(s >> 64), lo = (uint64_t)s;
        unsigned rot = (unsigned)(hi >> 58);
        uint64_t v = hi ^ lo;
        uint64_t o = (v >> rot) | (v << ((64u - rot) & 63u));
        uint32_t d0 = (uint32_t)o;
        uint32_t d1 = (uint32_t)(o >> 32);
        int i0 = base + 2 * t;
        if (i0 < 10000)       karr[i0] = (int)(((uint64_t)d0 * 3u) >> 32);
        else if (i0 < 20000)  darr[i0 - 10000] = (int)(((uint64_t)d0 * 5u) >> 32);
        int i1 = i0 + 1;
        if (i1 < 10000)       karr[i1] = (int)(((uint64_t)d1 * 3u) >> 32);
        else if (i1 < 20000)  darr[i1 - 10000] = (int)(((uint64_t)d1 * 5u) >> 32);
    }

    __syncthreads();   // karr/darr visible to the whole (single) block

    __shared__ int cnt[16], off[16], cur[16];
    if (tid < 16) cnt[tid] = 0;
    __syncthreads();
    for (int i = tid; i < N_KERNELS; i += 256)
        atomicAdd(&cnt[karr[i] * 5 + darr[i]], 1);
    __syncthreads();
    if (tid == 0) { int o = 0; for (int g = 0; g < 15; g++) { off[g] = o; o += cnt[g]; } }
    __syncthreads();
    if (tid < 16) cur[tid] = 0;
    __syncthreads();
    for (int i = tid; i < N_KERNELS; i += 256) {
        int g = karr[i] * 5 + darr[i];
        list[off[g] + atomicAdd(&cur[g], 1)] = i;
    }
    __syncthreads();
    if (tid == 0) {
        const int kv[3] = {7, 9, 11};
        int ci = 0;
        for (int g = 0; g < 15; g++) {
            int sz = cnt[g];
            for (int s2 = 0; s2 < sz; s2 += 256) {
                int4 e2;
                e2.x = kv[g / 5];
                e2.y = g % 5;
                e2.z = off[g] + s2;
                e2.w = (sz - s2 < 256) ? (sz - s2) : 256;
                reinterpret_cast<int4*>(sched)[ci++] = e2;
            }
        }
        for (; ci < NCHUNK; ci++) {
            int4 e2; e2.x = 0; e2.y = 0; e2.z = 0; e2.w = 0;
            reinterpret_cast<int4*>(sched)[ci] = e2;
        }
    }
}

// ---------------------------------------------------------------------------
// Main: bf16 MFMA Toeplitz GEMM (R6 coverage structure, verified correct).
// R11: manual x2 unroll of the position loop. The R10 rotating-register
// ping-pong (a=b copies, 12 v_movs/iter forced by unroll(1)) is replaced by
// two persistent frag sets used alternately; prefetch for it+2 issues right
// after set A's last MFMA use, it+3 after set B's. Peak live accum stays
// BT(32)+2 tiles(32); both frag sets were already simultaneously live in
// R10, so net register delta ~0 (occupancy must stay 4 blocks/CU).
// ---------------------------------------------------------------------------
__device__ __forceinline__ uint16_t f32_to_bf16(float v) {
    uint32_t u = __builtin_bit_cast(uint32_t, v);
    return (uint16_t)((u + 0x7FFFu + ((u >> 16) & 1u)) >> 16);
}

__device__ __forceinline__ void stat16(const floatx16& C, float& mx, int& cnt) {
    float g0 = fmaxf(fmaxf(C[0],  C[1]),  C[2]);
    float g1 = fmaxf(fmaxf(C[3],  C[4]),  C[5]);
    float g2 = fmaxf(fmaxf(C[6],  C[7]),  C[8]);
    float g3 = fmaxf(fmaxf(C[9],  C[10]), C[11]);
    float g4 = fmaxf(fmaxf(C[12], C[13]), C[14]);
    float h0 = fmaxf(fmaxf(g0, g1), g2);
    float h1 = fmaxf(fmaxf(g3, g4), C[15]);
    mx = fmaxf(mx, fmaxf(h0, h1));
    uint32_t mA = 0, mB = 0;
    #pragma unroll
    for (int i = 0; i < 16; i += 2) {
        mA = (mA << 1) | (__builtin_bit_cast(uint32_t, C[i])     >> 31);
        mB = (mB << 1) | (__builtin_bit_cast(uint32_t, C[i + 1]) >> 31);
    }
    cnt += __popc(mA) + __popc(mB);
}

__device__ __forceinline__ int swz_g(int g) { return g ^ ((g >> 4) & 3); }

template <int K, int D>
__device__ __forceinline__ void body(const float* __restrict__ x,
                                     const float* __restrict__ wgt,
                                     const float* __restrict__ bias,
                                     const int* __restrict__ list,
                                     int lstart, int valid,
                                     float* __restrict__ out,
                                     short* __restrict__ xs,   // [4][3][CH_ALLOC]
                                     int b) {
    constexpr int H   = (K - 1) / 2;
    constexpr int Q   = 1024 / D;
    constexpr int S   = Q + 16;                    // residue slot stride (gap 16)
    constexpr int RS  = (D <= 4) ? 8 : (D == 8 ? 4 : 2);   // row stride (positions)
    constexpr int NIT = 32;                        // total iterations (all D), even

    const int tid   = threadIdx.x;
    const int lane  = tid & 63;
    const int wave  = tid >> 6;
    const int jbase = (lane >> 5) * 8;             // k-half offset (0 or 8 shorts)
    const int m31   = lane & 31;                   // A row / C-D column index

    // ---- stage: 4 phase-copies, bank-swizzled at 8B-granule level ---------
    for (int idx = tid; idx < 3 * (CH_ALLOC + NPHASE); idx += 256) {
        int c = idx / (CH_ALLOC + NPHASE);
        int P = idx - c * (CH_ALLOC + NPHASE);
        float v = 0.f;
        int y = P - 8;
        if (y >= 0) {
            int r = y / S;
            int q = y - r * S;
            if (r < D && q < Q) v = x[((size_t)b * 3 + c) * 1024 + r + D * q];
        }
        short hv = (short)f32_to_bf16(v);
        #pragma unroll
        for (int pp = 0; pp < NPHASE; ++pp) {
            int ee = P - pp;
            if (ee >= 0 && ee < CH_ALLOC) {
                int phys = (swz_g(ee >> 2) << 2) | (ee & 3);
                xs[pp * PP_STRIDE + c * CH_ALLOC + phys] = hv;
            }
        }
    }

    // ---- per-lane B fragments (single bf16 weights), overlap staging ------
    int i0 = wave * 64 + m31;
    int i1 = i0 + 32;
    int n0 = list[lstart + (i0 < valid ? i0 : valid - 1)];
    int n1 = list[lstart + (i1 < valid ? i1 : valid - 1)];
    short8 whi[2][3];
    #pragma unroll
    for (int t2 = 0; t2 < 2; ++t2) {
        int n = t2 ? n1 : n0;
        #pragma unroll
        for (int c = 0; c < 3; ++c) {
            #pragma unroll
            for (int u = 0; u < 8; ++u) {
                int j = jbase + u;
                float wv = (j < 11) ? wgt[n * 33 + c * 11 + j] : 0.f;
                whi[t2][c][u] = (short)f32_to_bf16(wv);
            }
        }
    }
    float bv0 = bias[n0], bv1 = bias[n1];

    floatx16 BT0, BT1;                             // persistent bias seed tiles
    #pragma unroll
    for (int i = 0; i < 16; ++i) { BT0[i] = bv0; BT1[i] = bv1; }

    __syncthreads();

    // ---- window-start index for flattened iteration it --------------------
    auto calcF = [&](int it) -> int {
        int ri, p;
        if (D <= 4)      { ri = it >> 3; p = it & 7; }
        else if (D == 8) { ri = it >> 2; p = it & 3; }
        else             { ri = it >> 1; p = it & 1; }
        int q0;
        if (D == 1)      q0 = 8 + ri * 256;
        else if (D == 2) q0 = 8 + (ri >> 1) * S + (ri & 1) * 256;
        else             q0 = 8 + ri * S;
        return q0 + p - H + RS * m31;
    };
    // swizzled 2x b64 frag load (frag = logical shorts [(F&~3)+jbase, +8))
    auto loadfrag = [&](int F, short8& A0, short8& A1, short8& A2) {
        int g0 = (F >> 2) + (jbase >> 2);
        int s0 = swz_g(g0) << 2;
        int s1 = swz_g(g0 + 1) << 2;
        const short* bp = xs + (F & 3) * PP_STRIDE;
        short4v l0 = *reinterpret_cast<const short4v*>(bp + s0);
        short4v h0 = *reinterpret_cast<const short4v*>(bp + s1);
        short4v l1 = *reinterpret_cast<const short4v*>(bp + CH_ALLOC + s0);
        short4v h1 = *reinterpret_cast<const short4v*>(bp + CH_ALLOC + s1);
        short4v l2 = *reinterpret_cast<const short4v*>(bp + 2 * CH_ALLOC + s0);
        short4v h2 = *reinterpret_cast<const short4v*>(bp + 2 * CH_ALLOC + s1);
        A0 = __builtin_shufflevector(l0, h0, 0, 1, 2, 3, 4, 5, 6, 7);
        A1 = __builtin_shufflevector(l1, h1, 0, 1, 2, 3, 4, 5, 6, 7);
        A2 = __builtin_shufflevector(l2, h2, 0, 1, 2, 3, 4, 5, 6, 7);
    };

    // ---- main loop: manual x2 unroll, two persistent frag sets ------------
    float mx0 = -3.402823466e38f, mx1 = -3.402823466e38f;
    int cnt0 = 0, cnt1 = 0;                        // negative counts

    short8 a0, a1, a2, b0, b1, b2;
    loadfrag(calcF(0), a0, a1, a2);
    loadfrag(calcF(1), b0, b1, b2);

    #pragma unroll 1
    for (int it = 0; it < NIT; it += 2) {
        int itA = (it + 2 < NIT) ? it + 2 : NIT - 1;   // clamp (redundant reload)
        int itB = (it + 3 < NIT) ? it + 3 : NIT - 1;

        // ---- iteration it (frag set A) ----
        floatx16 C0, C1;
        C0 = __builtin_amdgcn_mfma_f32_32x32x16_bf16(a0, whi[0][0], BT0, 0, 0, 0);
        C0 = __builtin_amdgcn_mfma_f32_32x32x16_bf16(a1, whi[0][1], C0, 0, 0, 0);
        C0 = __builtin_amdgcn_mfma_f32_32x32x16_bf16(a2, whi[0][2], C0, 0, 0, 0);
        C1 = __builtin_amdgcn_mfma_f32_32x32x16_bf16(a0, whi[1][0], BT1, 0, 0, 0);
        C1 = __builtin_amdgcn_mfma_f32_32x32x16_bf16(a1, whi[1][1], C1, 0, 0, 0);
        C1 = __builtin_amdgcn_mfma_f32_32x32x16_bf16(a2, whi[1][2], C1, 0, 0, 0);
        loadfrag(calcF(itA), a0, a1, a2);           // set A free -> prefetch it+2
        stat16(C0, mx0, cnt0);
        stat16(C1, mx1, cnt1);

        // ---- iteration it+1 (frag set B) ----
        floatx16 D0, D1;
        D0 = __builtin_amdgcn_mfma_f32_32x32x16_bf16(b0, whi[0][0], BT0, 0, 0, 0);
        D0 = __builtin_amdgcn_mfma_f32_32x32x16_bf16(b1, whi[0][1], D0, 0, 0, 0);
        D0 = __builtin_amdgcn_mfma_f32_32x32x16_bf16(b2, whi[0][2], D0, 0, 0, 0);
        D1 = __builtin_amdgcn_mfma_f32_32x32x16_bf16(b0, whi[1][0], BT1, 0, 0, 0);
        D1 = __builtin_amdgcn_mfma_f32_32x32x16_bf16(b1, whi[1][1], D1, 0, 0, 0);
        D1 = __builtin_amdgcn_mfma_f32_32x32x16_bf16(b2, whi[1][2], D1, 0, 0, 0);
        loadfrag(calcF(itB), b0, b1, b2);           // set B free -> prefetch it+3
        stat16(D0, mx0, cnt0);
        stat16(D1, mx1, cnt1);
    }

    // ---- merge complementary row halves across the (L, L^32) lane pair ----
    mx0  = fmaxf(mx0, __shfl_xor(mx0, 32));
    mx1  = fmaxf(mx1, __shfl_xor(mx1, 32));
    cnt0 += __shfl_xor(cnt0, 32);
    cnt1 += __shfl_xor(cnt1, 32);

    if (lane < 32) {
        float2* ob = reinterpret_cast<float2*>(out + (size_t)b * (2 * N_KERNELS));
        ob[n0] = make_float2(mx0, (float)(1024 - cnt0) * (1.0f / 1024.0f));
        ob[n1] = make_float2(mx1, (float)(1024 - cnt1) * (1.0f / 1024.0f));
    }
}

__global__ __launch_bounds__(256, 4)
void rocket_main(const float* __restrict__ x, const float* __restrict__ wgt,
                 const float* __restrict__ bias, const int* __restrict__ list,
                 const int* __restrict__ sched, float* __restrict__ out) {
    __shared__ __align__(16) short xs[NPHASE * PP_STRIDE];   // 31.5 KB
    int4 e = reinterpret_cast<const int4*>(sched)[blockIdx.x];
    if (e.w == 0) return;                                // dead chunk — uniform exit
    int b = blockIdx.y;
    int kc = e.x, ld2 = e.y, lstart = e.z, valid = e.w;
    switch (kc * 8 + ld2) {
        case 7*8+0:  body<7, 1 >(x, wgt, bias, list, lstart, valid, out, xs, b); break;
        case 7*8+1:  body<7, 2 >(x, wgt, bias, list, lstart, valid, out, xs, b); break;
        case 7*8+2:  body<7, 4 >(x, wgt, bias, list, lstart, valid, out, xs, b); break;
        case 7*8+3:  body<7, 8 >(x, wgt, bias, list, lstart, valid, out, xs, b); break;
        case 7*8+4:  body<7, 16>(x, wgt, bias, list, lstart, valid, out, xs, b); break;
        case 9*8+0:  body<9, 1 >(x, wgt, bias, list, lstart, valid, out, xs, b); break;
        case 9*8+1:  body<9, 2 >(x, wgt, bias, list, lstart, valid, out, xs, b); break;
        case 9*8+2:  body<9, 4 >(x, wgt, bias, list, lstart, valid, out, xs, b); break;
        case 9*8+3:  body<9, 8 >(x, wgt, bias, list, lstart, valid, out, xs, b); break;
        case 9*8+4:  body<9, 16>(x, wgt, bias, list, lstart, valid, out, xs, b); break;
        case 11*8+0: body<11,1 >(x, wgt, bias, list, lstart, valid, out, xs, b); break;
        case 11*8+1: body<11,2 >(x, wgt, bias, list, lstart, valid, out, xs, b); break;
        case 11*8+2: body<11,4 >(x, wgt, bias, list, lstart, valid, out, xs, b); break;
        case 11*8+3: body<11,8 >(x, wgt, bias, list, lstart, valid, out, xs, b); break;
        default:     body<11,16>(x, wgt, bias, list, lstart, valid, out, xs, b); break;
    }
}

extern "C" void kernel_launch(void* const* d_in, const int* in_sizes, int n_in,
                              void* d_out, int out_size, void* d_ws, size_t ws_size,
                              hipStream_t stream) {
    const float* x   = (const float*)d_in[0];
    const float* w   = (const float*)d_in[1];
    const float* b   = (const float*)d_in[2];
    float* out = (float*)d_out;

    int* wsi  = (int*)d_ws;
    int* karr = wsi;            // 10000
    int* darr = wsi + 10000;    // 10000
    int* list = wsi + 20000;    // 10000
    int* schd = wsi + 30000;    // NCHUNK*4 ints (16B aligned)

    hipLaunchKernelGGL(setup_kernel, dim3(1), dim3(256), 0, stream,
                       karr, darr, list, schd);
    hipLaunchKernelGGL(rocket_main,  dim3(NCHUNK, 64), dim3(256), 0, stream,
                       x, w, b, list, schd, out);
}